// Round 1
// baseline (236.886 us; speedup 1.0000x reference)
//
#include <hip/hip_runtime.h>

typedef __bf16 bf16;
typedef __bf16 bf16x8 __attribute__((ext_vector_type(8)));
typedef float  f32x4  __attribute__((ext_vector_type(4)));

#define DEVI __device__ __forceinline__

static constexpr int   BATCH = 256;
static constexpr int   SEQ   = 256;
static constexpr int   CH    = 192;
static constexpr int   NH    = 6;
static constexpr int   AG    = 49;
static constexpr float QK_SCALE = 0.17677669529663687f;  // 32^-0.5

// ---- adaptive-avg-pool 16 -> 7: inverse bin tables (idx -> (bin, weight) x {1,2}) ----
__device__ constexpr int   PPN[16]  = {1,1,2,1,2,1,2,1,1,2,1,2,1,2,1,1};
__device__ constexpr int   PPB0[16] = {0,0,0,1,1,2,2,3,3,3,4,4,5,5,6,6};
__device__ constexpr int   PPB1[16] = {0,0,1,0,2,0,3,0,0,4,0,5,0,6,0,0};
__device__ constexpr float PPW0[16] = {1.f/3.f,1.f/3.f,1.f/3.f,1.f/3.f,1.f/3.f,1.f/3.f,1.f/3.f,0.25f,0.25f,0.25f,
                                       1.f/3.f,1.f/3.f,1.f/3.f,1.f/3.f,1.f/3.f,1.f/3.f};
__device__ constexpr float PPW1[16] = {0.f,0.f,1.f/3.f,0.f,1.f/3.f,0.f,0.25f,0.f,0.f,1.f/3.f,
                                       0.f,1.f/3.f,0.f,1.f/3.f,0.f,0.f};

// ---------------------------------------------------------------------------
// bilinear 7x7 -> 16x16 (align_corners=False), matches reference _resize_bilinear
DEVI float bilin7(const float* m, int i, int j) {
  float sh = (i + 0.5f) * 0.4375f - 0.5f; sh = sh < 0.f ? 0.f : sh;
  float sw = (j + 0.5f) * 0.4375f - 0.5f; sw = sw < 0.f ? 0.f : sw;
  int i0 = (int)sh; if (i0 > 6) i0 = 6;
  int j0 = (int)sw; if (j0 > 6) j0 = 6;
  int i1 = i0 + 1;  if (i1 > 6) i1 = 6;
  int j1 = j0 + 1;  if (j1 > 6) j1 = 6;
  float th = sh - (float)i0, tw = sw - (float)j0;
  float v00 = m[i0*7 + j0], v01 = m[i0*7 + j1];
  float v10 = m[i1*7 + j0], v11 = m[i1*7 + j1];
  return (v00*(1.f-tw) + v01*tw)*(1.f-th) + (v10*(1.f-tw) + v11*tw)*th;
}

// ---------------------------------------------------------------------------
// K1: weights->bf16, pb[h][a][n], ab[h][n][a], zero pads of a1/a2
__global__ void k_prep(const float* Wq, const float* Wk, const float* Wv,
                       const float* Wa1, const float* Wa2, const float* Wp,
                       const float* an_bias, const float* na_bias,
                       const float* ah_bias, const float* aw_bias,
                       const float* ha_bias, const float* wa_bias,
                       bf16* wsW, float* pb, float* ab, bf16* a1, bf16* a2) {
  int gid = blockIdx.x * 256 + threadIdx.x;
  if (gid < 221184) {                       // 6 x 192x192 weight converts
    int mi = gid / 36864, r = gid - mi * 36864;
    const float* W = (mi == 0 ? Wq : mi == 1 ? Wk : mi == 2 ? Wv :
                      mi == 3 ? Wa1 : mi == 4 ? Wa2 : Wp);
    wsW[gid] = (bf16)W[r];
  } else if (gid < 296448) {                // pb: [h][49][256]
    int r = gid - 221184;
    int n = r & 255, ha = r >> 8;           // ha = h*49 + a
    int i = n >> 4, j = n & 15;
    float val = bilin7(an_bias + (size_t)ha * 49, i, j)
              + ah_bias[ha * 16 + i] + aw_bias[ha * 16 + j];
    pb[r] = val;
  } else if (gid < 371712) {                // ab: [h][256][49]
    int r = gid - 296448;
    int a = r % 49, hn = r / 49;
    int n = hn & 255, hh = hn >> 8;
    int i = n >> 4, j = n & 15;
    float val = bilin7(na_bias + (size_t)(hh * 49 + a) * 49, i, j)
              + ha_bias[(hh * 16 + i) * 49 + a] + wa_bias[(hh * 16 + j) * 49 + a];
    ab[r] = val;
  } else if (gid < 396288) {                // zero 64 pad rows of a1,a2
    int r = gid - 371712;
    if (r < 12288) a1[(size_t)12544 * CH + r] = (bf16)0.f;
    else           a2[(size_t)12544 * CH + (r - 12288)] = (bf16)0.f;
  }
}

// ---------------------------------------------------------------------------
// K2: per-batch: k-input & v-input combos (bf16) + adaptive pooled x_C1/x_C2
__global__ __launch_bounds__(192) void k_combo_pool(
    const float* xF1, const float* xC2, const float* xC1,
    bf16* xKb, bf16* xVb, bf16* pooled1, bf16* pooled2) {
  __shared__ float pool[2][49][192];
  const int b = blockIdx.x, c = threadIdx.x;   // 192 threads, one channel each
  for (int idx = threadIdx.x; idx < 2 * 49 * 192; idx += 192)
    ((float*)pool)[idx] = 0.f;
  __syncthreads();

  const float* pf = xF1 + (size_t)b * SEQ * CH + c;
  const float* p2 = xC2 + (size_t)b * SEQ * CH + c;
  const float* p1 = xC1 + (size_t)b * SEQ * CH + c;
  bf16* ok = xKb + (size_t)b * SEQ * CH + c;
  bf16* ov = xVb + (size_t)b * SEQ * CH + c;

  for (int i = 0; i < 16; ++i) {
    float w1[7] = {0,0,0,0,0,0,0};
    float w2[7] = {0,0,0,0,0,0,0};
    #pragma unroll
    for (int j = 0; j < 16; ++j) {
      const int n = i * 16 + j;
      float f1 = pf[n * CH], c2 = p2[n * CH], c1 = p1[n * CH];
      ok[n * CH] = (bf16)(f1 + c2 - c1);
      ov[n * CH] = (bf16)(c2 - c1);
      w1[PPB0[j]] += PPW0[j] * c1;  w2[PPB0[j]] += PPW0[j] * c2;
      if (PPN[j] == 2) { w1[PPB1[j]] += PPW1[j] * c1;  w2[PPB1[j]] += PPW1[j] * c2; }
    }
    #pragma unroll 1
    for (int u = 0; u < PPN[i]; ++u) {
      const int p = (u == 0) ? PPB0[i] : PPB1[i];
      const float wt = (u == 0) ? PPW0[i] : PPW1[i];
      #pragma unroll
      for (int qq = 0; qq < 7; ++qq) {
        pool[0][p * 7 + qq][c] += wt * w1[qq];
        pool[1][p * 7 + qq][c] += wt * w2[qq];
      }
    }
  }
  __syncthreads();
  for (int a = 0; a < 49; ++a) {
    pooled1[((size_t)b * 49 + a) * CH + c] = (bf16)pool[0][a][c];
    pooled2[((size_t)b * 49 + a) * CH + c] = (bf16)pool[1][a][c];
  }
}

// ---------------------------------------------------------------------------
// shared GEMM body: C[M,192] = A[M,192] @ W^T + bias ; tile 128x192, 4 waves
template<bool F32SRC, bool F32OUT>
DEVI void gemm_body(const void* Asrc, const bf16* W, const float* bias,
                    void* outp, int m0, bf16 (*sA)[72]) {
  const int tid = threadIdx.x, lane = tid & 63, wid = tid >> 6;
  const int l15 = lane & 15, lg = lane >> 4;
  const int wr = wid >> 1, wc = wid & 1;
  const int srow = tid >> 1, shalf = tid & 1;

  f32x4 acc[4][6];
  #pragma unroll
  for (int a = 0; a < 4; ++a)
    #pragma unroll
    for (int b2 = 0; b2 < 6; ++b2) acc[a][b2] = f32x4{0.f, 0.f, 0.f, 0.f};

  for (int ks = 0; ks < 3; ++ks) {
    const int k0 = ks * 64;
    if (F32SRC) {
      const float4* src = (const float4*)((const float*)Asrc +
                          (size_t)(m0 + srow) * CH + k0 + shalf * 32);
      #pragma unroll
      for (int i2 = 0; i2 < 4; ++i2) {
        float4 lo = src[2 * i2], hi = src[2 * i2 + 1];
        bf16x8 t;
        t[0] = (bf16)lo.x; t[1] = (bf16)lo.y; t[2] = (bf16)lo.z; t[3] = (bf16)lo.w;
        t[4] = (bf16)hi.x; t[5] = (bf16)hi.y; t[6] = (bf16)hi.z; t[7] = (bf16)hi.w;
        *(bf16x8*)&sA[srow][shalf * 32 + 8 * i2] = t;
      }
    } else {
      const uint4* src = (const uint4*)((const bf16*)Asrc +
                         (size_t)(m0 + srow) * CH + k0 + shalf * 32);
      #pragma unroll
      for (int i2 = 0; i2 < 4; ++i2)
        *(uint4*)&sA[srow][shalf * 32 + 8 * i2] = src[i2];
    }
    __syncthreads();
    #pragma unroll
    for (int kk = 0; kk < 64; kk += 32) {
      bf16x8 af[4];
      #pragma unroll
      for (int rt = 0; rt < 4; ++rt)
        af[rt] = *(const bf16x8*)&sA[64 * wr + 16 * rt + l15][kk + 8 * lg];
      #pragma unroll
      for (int ct = 0; ct < 6; ++ct) {
        const int ncol = 96 * wc + 16 * ct + l15;
        bf16x8 bfr = *(const bf16x8*)&W[(size_t)ncol * CH + k0 + kk + 8 * lg];
        #pragma unroll
        for (int rt = 0; rt < 4; ++rt)
          acc[rt][ct] = __builtin_amdgcn_mfma_f32_16x16x32_bf16(af[rt], bfr, acc[rt][ct], 0, 0, 0);
      }
    }
    __syncthreads();
  }
  // epilogue: D row = (lane>>4)*4 + reg, col = lane&15
  #pragma unroll
  for (int ct = 0; ct < 6; ++ct) {
    const int col = 96 * wc + 16 * ct + l15;
    const float bb = bias[col];
    #pragma unroll
    for (int rt = 0; rt < 4; ++rt) {
      const size_t rbase = (size_t)(m0 + 64 * wr + 16 * rt + 4 * lg);
      #pragma unroll
      for (int r = 0; r < 4; ++r) {
        float v = acc[rt][ct][r] + bb;
        if (F32OUT) ((float*)outp)[(rbase + r) * CH + col] = v;
        else        ((bf16*)outp)[(rbase + r) * CH + col] = (bf16)v;
      }
    }
  }
}

// K3: 5 projection jobs via grid.y
__global__ __launch_bounds__(256, 2) void k_gemm5(
    const float* xF1, const bf16* xKb, const bf16* xVb,
    const bf16* pooled1, const bf16* pooled2, const bf16* wsW,
    const float* bq, const float* bk, const float* bv,
    const float* ba1, const float* ba2,
    bf16* q, bf16* k, bf16* v, bf16* a1, bf16* a2) {
  __shared__ bf16 sA[128][72] __attribute__((aligned(16)));
  const int job = blockIdx.y, tile = blockIdx.x;
  const int m0 = tile * 128;
  switch (job) {
    case 0: gemm_body<true , false>(xF1, wsW,             bq,  q,  m0, sA); break;
    case 1: gemm_body<false, false>(xKb, wsW + 36864,     bk,  k,  m0, sA); break;
    case 2: gemm_body<false, false>(xVb, wsW + 2 * 36864, bv,  v,  m0, sA); break;
    case 3: if (tile < 98) gemm_body<false, false>(pooled1, wsW + 3 * 36864, ba1, a1, m0, sA); break;
    case 4: if (tile < 98) gemm_body<false, false>(pooled2, wsW + 4 * 36864, ba2, a2, m0, sA); break;
  }
}

// K6: output projection (fp32 out)
__global__ __launch_bounds__(256, 2) void k_gemm_out(
    const bf16* xsum, const bf16* Wp, const float* bp, float* out) {
  __shared__ bf16 sA[128][72] __attribute__((aligned(16)));
  gemm_body<false, true>(xsum, Wp, bp, out, blockIdx.x * 128, sA);
}

// ---------------------------------------------------------------------------
// K4: fused two-stage agent attention per (b, h). 256 threads = 4 waves.
__global__ __launch_bounds__(256, 2) void k_attn(
    const bf16* q, const bf16* k, const bf16* v,
    const bf16* a1, const bf16* a2, const float* pb, const float* ab,
    bf16* xout) {
  const int h = blockIdx.x, b = blockIdx.y;
  __shared__ char uSmem[36864] __attribute__((aligned(16)));   // log1[64][264] | log2[256][72]
  bf16 (*log1)[264] = reinterpret_cast<bf16 (*)[264]>(uSmem);
  bf16 (*log2)[72]  = reinterpret_cast<bf16 (*)[72]>(uSmem);
  __shared__ bf16 sVT[32][264] __attribute__((aligned(16)));   // v transposed [d][n]
  __shared__ bf16 sAVT[32][72] __attribute__((aligned(16)));   // agent_v^T [d][a(64)]
  __shared__ float srow1[64];
  __shared__ float srow2[256];

  const int tid = threadIdx.x, lane = tid & 63, wv = tid >> 6;
  const int l15 = lane & 15, lg = lane >> 4;

  const bf16* qb  = q  + (size_t)b * SEQ * CH + h * 32;
  const bf16* kb  = k  + (size_t)b * SEQ * CH + h * 32;
  const bf16* vb  = v  + (size_t)b * SEQ * CH + h * 32;
  const bf16* a1b = a1 + (size_t)b * AG  * CH + h * 32;
  const bf16* a2b = a2 + (size_t)b * AG  * CH + h * 32;

  // ---- stage V^T into LDS (paired u32 writes, conflict-free) ----
  {
    const int p = tid & 127, dg = tid >> 7;   // two n-rows per thread, half the d's
    const bf16* s0 = vb + (size_t)(2 * p) * CH + dg * 16;
    bf16x8 r0a = ((const bf16x8*)s0)[0];
    bf16x8 r0b = ((const bf16x8*)s0)[1];
    bf16x8 r1a = ((const bf16x8*)(s0 + CH))[0];
    bf16x8 r1b = ((const bf16x8*)(s0 + CH))[1];
    #pragma unroll
    for (int j = 0; j < 8; ++j) {
      union { bf16 e[2]; unsigned u; } u0, u1;
      u0.e[0] = r0a[j]; u0.e[1] = r1a[j];
      u1.e[0] = r0b[j]; u1.e[1] = r1b[j];
      *(unsigned*)&sVT[dg * 16 + j][2 * p]     = u0.u;
      *(unsigned*)&sVT[dg * 16 + 8 + j][2 * p] = u1.u;
    }
  }

  // ---- stage-1 logits: D[a(64)][n(256)], wave wv -> n in [64wv, 64wv+64) ----
  {
    bf16x8 afr[4];
    #pragma unroll
    for (int rt = 0; rt < 4; ++rt)
      afr[rt] = *(const bf16x8*)(a2b + (size_t)(16 * rt + l15) * CH + 8 * lg);
    #pragma unroll
    for (int ct = 0; ct < 4; ++ct) {
      const int n = 64 * wv + 16 * ct + l15;
      bf16x8 bfr = *(const bf16x8*)(kb + (size_t)n * CH + 8 * lg);
      #pragma unroll
      for (int rt = 0; rt < 4; ++rt) {
        f32x4 acc = {0.f, 0.f, 0.f, 0.f};
        acc = __builtin_amdgcn_mfma_f32_16x16x32_bf16(afr[rt], bfr, acc, 0, 0, 0);
        #pragma unroll
        for (int r = 0; r < 4; ++r)
          log1[16 * rt + 4 * lg + r][n] = (bf16)acc[r];
      }
    }
  }
  __syncthreads();

  // ---- softmax over n (rows a<49); store unnormalized e, srow1 = 1/sum ----
  if (tid < 196) {
    const int a = tid >> 2, qu = tid & 3;
    const float* pbrow = pb + ((size_t)h * AG + a) * SEQ + qu * 64;
    float vbuf[64];
    float m = -1e30f;
    #pragma unroll
    for (int i2 = 0; i2 < 8; ++i2) {
      bf16x8 raw = *(const bf16x8*)&log1[a][qu * 64 + 8 * i2];
      #pragma unroll
      for (int j = 0; j < 8; ++j) {
        float x = QK_SCALE * (float)raw[j] + pbrow[8 * i2 + j];
        vbuf[8 * i2 + j] = x;
        m = fmaxf(m, x);
      }
    }
    m = fmaxf(m, __shfl_xor(m, 1));
    m = fmaxf(m, __shfl_xor(m, 2));
    float s = 0.f;
    #pragma unroll
    for (int i2 = 0; i2 < 8; ++i2) {
      bf16x8 eb;
      #pragma unroll
      for (int j = 0; j < 8; ++j) {
        float e = __expf(vbuf[8 * i2 + j] - m);
        s += e;
        eb[j] = (bf16)e;
      }
      *(bf16x8*)&log1[a][qu * 64 + 8 * i2] = eb;
    }
    s += __shfl_xor(s, 1);
    s += __shfl_xor(s, 2);
    if (qu == 0) srow1[a] = 1.f / s;
  }
  __syncthreads();

  // ---- PV1: agent_v[a][d] = (e @ V) * 1/s ; wave wv owns a in [16wv,16wv+16) ----
  {
    f32x4 acc0 = {0.f, 0.f, 0.f, 0.f}, acc1 = {0.f, 0.f, 0.f, 0.f};
    #pragma unroll
    for (int ksn = 0; ksn < 8; ++ksn) {
      bf16x8 af = *(const bf16x8*)&log1[16 * wv + l15][32 * ksn + 8 * lg];
      bf16x8 b0 = *(const bf16x8*)&sVT[l15][32 * ksn + 8 * lg];
      bf16x8 b1 = *(const bf16x8*)&sVT[16 + l15][32 * ksn + 8 * lg];
      acc0 = __builtin_amdgcn_mfma_f32_16x16x32_bf16(af, b0, acc0, 0, 0, 0);
      acc1 = __builtin_amdgcn_mfma_f32_16x16x32_bf16(af, b1, acc1, 0, 0, 0);
    }
    #pragma unroll
    for (int r = 0; r < 4; ++r) {
      const int a = 16 * wv + 4 * lg + r;
      const float inv = (a < AG) ? srow1[a] : 0.f;
      sAVT[l15][a]      = (bf16)(acc0[r] * inv);
      sAVT[16 + l15][a] = (bf16)(acc1[r] * inv);
    }
  }
  __syncthreads();   // AVT ready; log1 dead -> log2 may be written

  // ---- stage-2 logits: D[nq(256)][a(64)]; wave wv -> nq in [64wv, 64wv+64) ----
  {
    bf16x8 bfr[4];
    #pragma unroll
    for (int ct = 0; ct < 4; ++ct)
      bfr[ct] = *(const bf16x8*)(a1b + (size_t)(16 * ct + l15) * CH + 8 * lg);
    #pragma unroll
    for (int rt = 0; rt < 4; ++rt) {
      bf16x8 af = *(const bf16x8*)(qb + (size_t)(64 * wv + 16 * rt + l15) * CH + 8 * lg);
      #pragma unroll
      for (int ct = 0; ct < 4; ++ct) {
        f32x4 acc = {0.f, 0.f, 0.f, 0.f};
        acc = __builtin_amdgcn_mfma_f32_16x16x32_bf16(af, bfr[ct], acc, 0, 0, 0);
        #pragma unroll
        for (int r = 0; r < 4; ++r)
          log2[64 * wv + 16 * rt + 4 * lg + r][16 * ct + l15] = (bf16)acc[r];
      }
    }
  }
  __syncthreads();

  // ---- softmax over a (49) per row nq = tid; cols 49..63 zeroed ----
  {
    const float* abrow = ab + ((size_t)h * SEQ + tid) * AG;
    float vb2[49];
    float m = -1e30f;
    #pragma unroll
    for (int i2 = 0; i2 < 6; ++i2) {
      bf16x8 raw = *(const bf16x8*)&log2[tid][8 * i2];
      #pragma unroll
      for (int j = 0; j < 8; ++j) {
        float x = QK_SCALE * (float)raw[j] + abrow[8 * i2 + j];
        vb2[8 * i2 + j] = x;
        m = fmaxf(m, x);
      }
    }
    {
      float x = QK_SCALE * (float)log2[tid][48] + abrow[48];
      vb2[48] = x;
      m = fmaxf(m, x);
    }
    float s = 0.f;
    #pragma unroll
    for (int i2 = 0; i2 < 8; ++i2) {
      bf16x8 eb;
      #pragma unroll
      for (int j = 0; j < 8; ++j) {
        const int idx = 8 * i2 + j;
        float e = 0.f;
        if (idx < AG) { e = __expf(vb2[idx] - m); }
        s += e;
        eb[j] = (bf16)e;
      }
      *(bf16x8*)&log2[tid][8 * i2] = eb;
    }
    srow2[tid] = 1.f / s;
  }
  __syncthreads();

  // ---- PV2: x[nq][d] = (e2 @ agent_v) * 1/s2 -> global bf16 ----
  {
    bf16x8 bfr[2][2];
    #pragma unroll
    for (int ksn = 0; ksn < 2; ++ksn) {
      bfr[ksn][0] = *(const bf16x8*)&sAVT[l15][32 * ksn + 8 * lg];
      bfr[ksn][1] = *(const bf16x8*)&sAVT[16 + l15][32 * ksn + 8 * lg];
    }
    bf16* outp = xout + (size_t)b * SEQ * CH + h * 32;
    #pragma unroll
    for (int rt = 0; rt < 4; ++rt) {
      f32x4 acc0 = {0.f, 0.f, 0.f, 0.f}, acc1 = {0.f, 0.f, 0.f, 0.f};
      #pragma unroll
      for (int ksn = 0; ksn < 2; ++ksn) {
        bf16x8 af = *(const bf16x8*)&log2[64 * wv + 16 * rt + l15][32 * ksn + 8 * lg];
        acc0 = __builtin_amdgcn_mfma_f32_16x16x32_bf16(af, bfr[ksn][0], acc0, 0, 0, 0);
        acc1 = __builtin_amdgcn_mfma_f32_16x16x32_bf16(af, bfr[ksn][1], acc1, 0, 0, 0);
      }
      #pragma unroll
      for (int r = 0; r < 4; ++r) {
        const int nq = 64 * wv + 16 * rt + 4 * lg + r;
        const float inv = srow2[nq];
        outp[(size_t)nq * CH + l15]      = (bf16)(acc0[r] * inv);
        outp[(size_t)nq * CH + 16 + l15] = (bf16)(acc1[r] * inv);
      }
    }
  }
}

// ---------------------------------------------------------------------------
// K5: xsum = x_attn + depthwise3x3(q) + dwc_b  (per (half-image, b) WG)
DEVI void fma8(float* acc, bf16x8 qv, float4 wa, float4 wb) {
  acc[0] += (float)qv[0] * wa.x; acc[1] += (float)qv[1] * wa.y;
  acc[2] += (float)qv[2] * wa.z; acc[3] += (float)qv[3] * wa.w;
  acc[4] += (float)qv[4] * wb.x; acc[5] += (float)qv[5] * wb.y;
  acc[6] += (float)qv[6] * wb.z; acc[7] += (float)qv[7] * wb.w;
}

__global__ __launch_bounds__(256) void k_dwconv(
    const bf16* q, const bf16* xattn, const float* dwc_w, const float* dwc_b,
    bf16* xsum) {
  __shared__ bf16 sQ[144][200] __attribute__((aligned(16)));
  __shared__ float sW[9][192] __attribute__((aligned(16)));
  const int half = blockIdx.x, b = blockIdx.y;
  const int t = threadIdx.x;
  const int base_n = half ? 112 : 0;   // staged q rows [base_n, base_n+144)

  if (t < 144) {
    const bf16* qs = q + ((size_t)b * SEQ + base_n + t) * CH;
    #pragma unroll
    for (int i2 = 0; i2 < 24; ++i2)
      *(uint4*)&sQ[t][8 * i2] = ((const uint4*)qs)[i2];
  }
  for (int idx = t; idx < 9 * 192; idx += 256) {
    int cc = idx / 9, tap = idx - cc * 9;
    sW[tap][cc] = dwc_w[idx];
  }
  __syncthreads();

  const int nloc = t & 127, chalf = t >> 7;
  const int n = half * 128 + nloc;
  const int ii = n >> 4, jj = n & 15;
  const bf16* xa = xattn + ((size_t)b * SEQ + n) * CH;
  bf16* xo = xsum + ((size_t)b * SEQ + n) * CH;
  const int c_base = chalf * 96;

  for (int c0 = c_base; c0 < c_base + 96; c0 += 8) {
    float accv[8];
    {
      const float4* bsrc = (const float4*)(dwc_b + c0);
      float4 b0 = bsrc[0], b1 = bsrc[1];
      accv[0] = b0.x; accv[1] = b0.y; accv[2] = b0.z; accv[3] = b0.w;
      accv[4] = b1.x; accv[5] = b1.y; accv[6] = b1.z; accv[7] = b1.w;
    }
    {
      bf16x8 xv = *(const bf16x8*)(xa + c0);
      #pragma unroll
      for (int j = 0; j < 8; ++j) accv[j] += (float)xv[j];
    }
    #pragma unroll
    for (int di = 0; di < 3; ++di) {
      const int i2 = ii + di - 1;
      if ((unsigned)i2 >= 16u) continue;
      #pragma unroll
      for (int dj = 0; dj < 3; ++dj) {
        const int j2 = jj + dj - 1;
        if ((unsigned)j2 >= 16u) continue;
        const int nn = i2 * 16 + j2 - base_n;
        bf16x8 qv = *(const bf16x8*)&sQ[nn][c0];
        const float4* wv4 = (const float4*)&sW[di * 3 + dj][c0];
        fma8(accv, qv, wv4[0], wv4[1]);
      }
    }
    bf16x8 ob;
    #pragma unroll
    for (int j = 0; j < 8; ++j) ob[j] = (bf16)accv[j];
    *(bf16x8*)(xo + c0) = ob;
  }
}

// ---------------------------------------------------------------------------
extern "C" void kernel_launch(void* const* d_in, const int* in_sizes, int n_in,
                              void* d_out, int out_size, void* d_ws, size_t ws_size,
                              hipStream_t stream) {
  (void)in_sizes; (void)n_in; (void)out_size; (void)ws_size;
  const float* xF1 = (const float*)d_in[0];
  const float* xC2 = (const float*)d_in[1];
  const float* xC1 = (const float*)d_in[2];
  const float* Wq  = (const float*)d_in[3];
  const float* bq  = (const float*)d_in[4];
  const float* Wk  = (const float*)d_in[5];
  const float* bk  = (const float*)d_in[6];
  const float* Wv  = (const float*)d_in[7];
  const float* bv  = (const float*)d_in[8];
  const float* Wa1 = (const float*)d_in[9];
  const float* ba1 = (const float*)d_in[10];
  const float* Wa2 = (const float*)d_in[11];
  const float* ba2 = (const float*)d_in[12];
  const float* an_bias = (const float*)d_in[13];
  const float* na_bias = (const float*)d_in[14];
  const float* ah_bias = (const float*)d_in[15];
  const float* aw_bias = (const float*)d_in[16];
  const float* ha_bias = (const float*)d_in[17];
  const float* wa_bias = (const float*)d_in[18];
  const float* dwc_w = (const float*)d_in[19];
  const float* dwc_b = (const float*)d_in[20];
  const float* Wp  = (const float*)d_in[21];
  const float* bp  = (const float*)d_in[22];

  char* ws = (char*)d_ws;
  size_t off = 0;
  auto nxt = [&](size_t bytes) -> char* {
    char* p = ws + off;
    off = (off + bytes + 255) & ~(size_t)255;
    return p;
  };
  const size_t XSZ = (size_t)BATCH * SEQ * CH;       // 12,582,912
  const size_t ASZ = ((size_t)BATCH * AG + 64) * CH; // padded agent rows

  bf16*  wsW     = (bf16*)nxt(6 * 36864 * sizeof(bf16));
  float* pb      = (float*)nxt(6 * 49 * 256 * sizeof(float));
  float* ab      = (float*)nxt(6 * 256 * 49 * sizeof(float));
  bf16*  xKb     = (bf16*)nxt(XSZ * sizeof(bf16));
  bf16*  xVb     = (bf16*)nxt(XSZ * sizeof(bf16));
  bf16*  pooled1 = (bf16*)nxt(ASZ * sizeof(bf16));
  bf16*  pooled2 = (bf16*)nxt(ASZ * sizeof(bf16));
  bf16*  qB      = (bf16*)nxt(XSZ * sizeof(bf16));
  bf16*  kB      = (bf16*)nxt(XSZ * sizeof(bf16));
  bf16*  vB      = (bf16*)nxt(XSZ * sizeof(bf16));
  bf16*  a1B     = (bf16*)nxt(ASZ * sizeof(bf16));
  bf16*  a2B     = (bf16*)nxt(ASZ * sizeof(bf16));
  bf16*  xattn   = xVb;   // dead after gemm5 job2
  bf16*  xsum    = xKb;   // dead after gemm5 job1

  k_prep<<<1548, 256, 0, stream>>>(Wq, Wk, Wv, Wa1, Wa2, Wp,
                                   an_bias, na_bias, ah_bias, aw_bias,
                                   ha_bias, wa_bias, wsW, pb, ab, a1B, a2B);
  k_combo_pool<<<BATCH, 192, 0, stream>>>(xF1, xC2, xC1, xKb, xVb, pooled1, pooled2);
  k_gemm5<<<dim3(512, 5), 256, 0, stream>>>(xF1, xKb, xVb, pooled1, pooled2, wsW,
                                            bq, bk, bv, ba1, ba2,
                                            qB, kB, vB, a1B, a2B);
  k_attn<<<dim3(NH, BATCH), 256, 0, stream>>>(qB, kB, vB, a1B, a2B, pb, ab, xattn);
  k_dwconv<<<dim3(2, BATCH), 256, 0, stream>>>(qB, xattn, dwc_w, dwc_b, xsum);
  k_gemm_out<<<512, 256, 0, stream>>>(xsum, wsW + 5 * 36864, bp, (float*)d_out);
}